// Round 1
// baseline (165.416 us; speedup 1.0000x reference)
//
#include <hip/hip_runtime.h>

#define NROWS 8192
#define BQ    4096
#define DDIM  256
#define INV_T (1.0f/0.07f)
#define K2EXP (1.4426950408889634f/0.07f)   // log2(e)/T

typedef short bf16x8 __attribute__((ext_vector_type(8)));
typedef float f32x4  __attribute__((ext_vector_type(4)));
typedef unsigned short u16;

__device__ __forceinline__ u16 f2bf(float f) {
  unsigned u = __float_as_uint(f);
  u += 0x7fffu + ((u >> 16) & 1u);   // round-to-nearest-even
  return (u16)(u >> 16);
}

// ---------------- kernel 1: L2-normalize rows of [z_i; z_j], cast to bf16 ----
// Also zeroes the scalar output (replaces the hipMemsetAsync graph node; safe
// because launches are stream-ordered and loss_kernel runs last).
__global__ void norm_cast_kernel(const float* __restrict__ zi,
                                 const float* __restrict__ zj,
                                 u16* __restrict__ zb,
                                 float* __restrict__ out) {
  if (blockIdx.x == 0 && threadIdx.x == 0) *out = 0.0f;
  int wave = threadIdx.x >> 6;
  int lane = threadIdx.x & 63;
  int row  = blockIdx.x * 4 + wave;            // one wave per row, 4 rows/block
  const float* src = (row < BQ) ? (zi + (size_t)row * DDIM)
                                : (zj + (size_t)(row - BQ) * DDIM);
  float4 v = ((const float4*)src)[lane];       // 64 lanes x float4 = 256
  float s = v.x*v.x + v.y*v.y + v.z*v.z + v.w*v.w;
  #pragma unroll
  for (int m = 32; m; m >>= 1) s += __shfl_xor(s, m, 64);
  float scale = 1.0f / fmaxf(sqrtf(s), 1e-12f);
  ushort4 o;
  o.x = f2bf(v.x * scale); o.y = f2bf(v.y * scale);
  o.z = f2bf(v.z * scale); o.w = f2bf(v.w * scale);
  ((ushort4*)(zb + (size_t)row * DDIM))[lane] = o;
}

// ---------------- kernel 2: fused sim GEMM + mask + pos/negexp row partials --
#define GL2LDS(gp, lp) \
  __builtin_amdgcn_global_load_lds((__attribute__((address_space(1))) void*)(gp), \
                                   (__attribute__((address_space(3))) void*)(lp), 16, 0, 0)

// Structure (round 3): the old version staged A AND B into LDS every BK=32
// step with TWO __syncthreads (vmcnt(0) drain each, zero prefetch distance)
// -> 64 steps x 2 barriers x full L2 latency exposed = latency-bound at
// MfmaUtil 23%. New version:
//   * A-tile (128x256, 64KB) staged into LDS ONCE via global_load_lds, then
//     a single __syncthreads -- the ONLY barrier in the kernel.
//   * B fragments stream global->registers per wave (each wave owns its own
//     cols; panels are L2-hot across the 64 row-blocks), depth-2 prefetch.
//   * A fragments double-buffered in regs from LDS (reused 4x across mi).
// lsA swizzle: row r's 16B chunk c stored at slot c ^ (r&7). ds_read_b128 at
// fixed (kk,qd) hits rows base..base+15 (stride 512B == same banks); the XOR
// spreads each 8-lane group over 8 distinct 16B slots -> conflict-free.
// global_load_lds writes linearly (base+lane*16), so the swizzle is applied
// by permuting the per-lane GLOBAL source chunk (guide m173 pattern).
//
// NOTE: __launch_bounds__(256, 2) -- min-waves 2 caps the unified VGPR file
// at 256/wave (we need ~230: 64 acc + 80 av/bv + 32 pos/neg + ...). Do NOT
// use 4: a 128-reg cap spills the accumulator (round-2 post-mortem, 620 MB
// of scratch traffic).
__global__ __launch_bounds__(256, 2) void simloss_kernel(
    const u16* __restrict__ zb, const int* __restrict__ labels,
    float* __restrict__ pos_p, float* __restrict__ neg_p) {
  __shared__ __align__(16) u16 lsA[128 * 256];   // 64 KB -> 2 blocks/CU

  const int tid  = threadIdx.x;
  const int w    = tid >> 6;         // wave 0..3
  const int lane = tid & 63;
  const int ln   = lane & 15;        // MFMA n/m lane index
  const int qd   = lane >> 4;        // MFMA quad
  const int wr   = w >> 1;           // wave row (0..1) in 2x2 wave grid
  const int wc   = w & 1;            // wave col
  const int r0   = blockIdx.x * 128; // block row base (64 row tiles)
  const int cb   = blockIdx.y * 1024;// col split base (8 splits)

  // ---- stage A once: rows r0..r0+127, full K=256, chunk-swizzled ----------
  #pragma unroll
  for (int j = 0; j < 16; ++j) {
    int base = w * 32 + j * 2;                 // each instr covers 2 rows
    int row  = base + (lane >> 5);
    int gcol = ((lane & 31) ^ (row & 7)) * 8;  // inverse-swizzled source chunk
    GL2LDS(zb + (size_t)(r0 + row) * DDIM + gcol, &lsA[base * 256]);
  }

  int rowlab[16];
  #pragma unroll
  for (int ri = 0; ri < 4; ++ri)
    #pragma unroll
    for (int r = 0; r < 4; ++r) {
      int row = r0 + wr * 64 + ri * 16 + qd * 4 + r;   // C/D: row = quad*4+reg
      rowlab[ri * 4 + r] = labels[row & (BQ - 1)];     // concat labels = labels[row % B]
    }

  float posA[16], negA[16];
  #pragma unroll
  for (int i = 0; i < 16; ++i) { posA[i] = 0.0f; negA[i] = 0.0f; }

  const int axor = ln & 7;                     // == (local A row) & 7
  int arow[4];
  #pragma unroll
  for (int ri = 0; ri < 4; ++ri) arow[ri] = (wr * 64 + ri * 16 + ln) * DDIM;

  __syncthreads();   // drains vmcnt (A staged by all waves) + barrier. Only one.

  for (int ci = 0; ci < 8; ++ci) {             // 8 x 128 cols per block
    const int c0 = cb + ci * 128;
    int colv[4], clab[4];
    const u16* bp[4];
    #pragma unroll
    for (int mi = 0; mi < 4; ++mi) {
      colv[mi] = c0 + wc * 64 + mi * 16 + ln;  // C/D: col = lane&15
      clab[mi] = labels[colv[mi] & (BQ - 1)];
      bp[mi]   = zb + (size_t)colv[mi] * DDIM + qd * 8;  // B[n=ln][k=qd*8+j]
    }

    const f32x4 z4 = {0.f, 0.f, 0.f, 0.f};
    f32x4 acc[4][4];
    #pragma unroll
    for (int ri = 0; ri < 4; ++ri)
      #pragma unroll
      for (int mi = 0; mi < 4; ++mi) acc[ri][mi] = z4;

    // register pipeline: A double-buffered (LDS ~120cy), B triple (L2 ~250cy)
    bf16x8 av[2][4], bv[3][4];
    #pragma unroll
    for (int ri = 0; ri < 4; ++ri)
      av[0][ri] = *(const bf16x8*)&lsA[arow[ri] + (qd ^ axor) * 8];
    #pragma unroll
    for (int mi = 0; mi < 4; ++mi) bv[0][mi] = *(const bf16x8*)(bp[mi]);
    #pragma unroll
    for (int mi = 0; mi < 4; ++mi) bv[1][mi] = *(const bf16x8*)(bp[mi] + 32);

    #pragma unroll
    for (int kk = 0; kk < 8; ++kk) {           // K = 256, BK = 32, fully unrolled
      if (kk < 7) {
        #pragma unroll
        for (int ri = 0; ri < 4; ++ri)
          av[(kk + 1) & 1][ri] = *(const bf16x8*)
              &lsA[arow[ri] + ((((kk + 1) * 4 + qd) ^ axor)) * 8];
      }
      if (kk < 6) {
        #pragma unroll
        for (int mi = 0; mi < 4; ++mi)         // imm-offset folded (compile-time kk)
          bv[(kk + 2) % 3][mi] = *(const bf16x8*)(bp[mi] + (kk + 2) * 32);
      }
      #pragma unroll
      for (int ri = 0; ri < 4; ++ri)
        #pragma unroll
        for (int mi = 0; mi < 4; ++mi)
          acc[ri][mi] = __builtin_amdgcn_mfma_f32_16x16x32_bf16(
              av[kk & 1][ri], bv[kk % 3][mi], acc[ri][mi], 0, 0, 0);
    }

    // fused epilogue: mask + accumulate per-row pos (raw dot) and neg (exp).
    // Self-exclusion test only exists in the 64 diagonal blocks (wave-uniform).
    if (r0 == c0) {
      #pragma unroll
      for (int ri = 0; ri < 4; ++ri)
        #pragma unroll
        for (int mi = 0; mi < 4; ++mi) {
          f32x4 v = acc[ri][mi];
          #pragma unroll
          for (int r = 0; r < 4; ++r) {
            int slt = ri * 4 + r;
            float s = v[r];
            bool same = (rowlab[slt] == clab[mi]);
            bool diag = ((r0 + wr * 64 + ri * 16 + qd * 4 + r) == colv[mi]);
            posA[slt] += (same && !diag) ? s : 0.0f;
            negA[slt] += same ? 0.0f : __builtin_amdgcn_exp2f(s * K2EXP);
          }
        }
    } else {
      #pragma unroll
      for (int ri = 0; ri < 4; ++ri)
        #pragma unroll
        for (int mi = 0; mi < 4; ++mi) {
          f32x4 v = acc[ri][mi];
          #pragma unroll
          for (int r = 0; r < 4; ++r) {
            int slt = ri * 4 + r;
            float s = v[r];
            bool same = (rowlab[slt] == clab[mi]);
            posA[slt] += same ? s : 0.0f;
            negA[slt] += same ? 0.0f : __builtin_amdgcn_exp2f(s * K2EXP);
          }
        }
    }
  }

  // reduce over the 16 lanes (ln) that hold different cols of the same row
  #pragma unroll
  for (int i = 0; i < 16; ++i) {
    #pragma unroll
    for (int m = 1; m < 16; m <<= 1) {
      posA[i] += __shfl_xor(posA[i], m, 64);
      negA[i] += __shfl_xor(negA[i], m, 64);
    }
  }
  if (ln == 0) {
    int s = blockIdx.y * 2 + wc;               // 16 disjoint slices
    #pragma unroll
    for (int i = 0; i < 16; ++i) {
      int row = r0 + wr * 64 + (i >> 2) * 16 + qd * 4 + (i & 3);
      pos_p[(size_t)s * NROWS + row] = posA[i];
      neg_p[(size_t)s * NROWS + row] = negA[i];
    }
  }
}

// ---------------- kernel 3: per-row loss + mean (parallel, atomic) -----------
__global__ void loss_kernel(const float* __restrict__ pos_p,
                            const float* __restrict__ neg_p,
                            float* __restrict__ out) {
  int row = blockIdx.x * 256 + threadIdx.x;      // 32 blocks x 256 threads
  float p = 0.0f, n = 0.0f;
  #pragma unroll
  for (int s = 0; s < 16; ++s) {
    p += pos_p[(size_t)s * NROWS + row];
    n += neg_p[(size_t)s * NROWS + row];
  }
  float l = log1pf(expf(logf(n) - p * INV_T));
  #pragma unroll
  for (int m = 32; m; m >>= 1) l += __shfl_xor(l, m, 64);
  __shared__ float red[4];
  if ((threadIdx.x & 63) == 0) red[threadIdx.x >> 6] = l;
  __syncthreads();
  if (threadIdx.x == 0) {
    float tot = red[0] + red[1] + red[2] + red[3];
    atomicAdd(out, tot * (1.0f / NROWS));
  }
}

// ---------------- launcher ---------------------------------------------------
extern "C" void kernel_launch(void* const* d_in, const int* in_sizes, int n_in,
                              void* d_out, int out_size, void* d_ws, size_t ws_size,
                              hipStream_t stream) {
  const float* zi     = (const float*)d_in[0];
  const float* zj     = (const float*)d_in[1];
  const int*   labels = (const int*)d_in[2];
  float*       out    = (float*)d_out;

  char* w = (char*)d_ws;
  u16*   zb    = (u16*)w;                                          // 4 MB bf16 Z
  float* pos_p = (float*)(w + (size_t)NROWS * DDIM * sizeof(u16)); // 16x8192 f32
  float* neg_p = pos_p + 16 * NROWS;                               // 16x8192 f32

  hipLaunchKernelGGL(norm_cast_kernel, dim3(2048), dim3(256), 0, stream,
                     zi, zj, zb, out);
  hipLaunchKernelGGL(simloss_kernel, dim3(64, 8), dim3(256), 0, stream,
                     zb, labels, pos_p, neg_p);
  hipLaunchKernelGGL(loss_kernel, dim3(32), dim3(256), 0, stream,
                     pos_p, neg_p, out);
}